// Round 1
// baseline (494.380 us; speedup 1.0000x reference)
//
#include <hip/hip_runtime.h>
#include <stdint.h>

#define NHEADS 16
#define EDIM   1024
#define SEQ    2048
#define BATCH  4

typedef float  floatx4 __attribute__((ext_vector_type(4)));
typedef __bf16 bf16x8  __attribute__((ext_vector_type(8)));
typedef unsigned short u16;

__device__ __forceinline__ u16 f2bf(float f) {
  union { float f; unsigned int u; } v; v.f = f;
  return (u16)((v.u + 0x7fffu + ((v.u >> 16) & 1u)) >> 16);
}

__device__ __forceinline__ void gl2lds16(const u16* g, u16* l) {
  __builtin_amdgcn_global_load_lds(
      (const __attribute__((address_space(1))) unsigned int*)g,
      (__attribute__((address_space(3))) unsigned int*)l, 16, 0, 0);
}

// ---------------- fp32 -> bf16 conversion ----------------
__global__ void cvt_bf16(const float* __restrict__ src, u16* __restrict__ dst, int n4) {
  int i = blockIdx.x * blockDim.x + threadIdx.x;
  const int stride = gridDim.x * blockDim.x;
  for (; i < n4; i += stride) {
    float4 f = ((const float4*)src)[i];
    ushort4 o;
    o.x = f2bf(f.x); o.y = f2bf(f.y); o.z = f2bf(f.z); o.w = f2bf(f.w);
    ((ushort4*)dst)[i] = o;
  }
}

// ---------------- GEMM: C[M,N] = A[M,K] * B[N,K]^T (bf16 in, fp32 acc) ------
// MODE 0: N=3072 fused QKV -> bf16 stores into Q (scaled 0.125), K, V buffers
// MODE 1: fp32 store to Cq
template <int MODE>
__global__ __launch_bounds__(256, 2)
void gemm_bt(const u16* __restrict__ A, const u16* __restrict__ B,
             void* __restrict__ Cq, u16* __restrict__ Ck, u16* __restrict__ Cv,
             int Kdim) {
  __shared__ u16 As[128 * 64];
  __shared__ u16 Bs[128 * 64];
  const int tid  = threadIdx.x;
  const int w    = tid >> 6, lane = tid & 63;
  const int quad = lane >> 4, l15 = lane & 15;
  const int sr   = lane >> 3, sc  = (lane & 7) * 8;
  const int rowA0 = blockIdx.y * 128, rowB0 = blockIdx.x * 128;
  const int wrow  = (w >> 1) * 64,    wcol  = (w & 1) * 64;

  const floatx4 vzero = {0.f, 0.f, 0.f, 0.f};
  floatx4 acc[4][4];
#pragma unroll
  for (int mi = 0; mi < 4; ++mi)
#pragma unroll
    for (int ni = 0; ni < 4; ++ni) acc[mi][ni] = vzero;

  for (int k0 = 0; k0 < Kdim; k0 += 64) {
    __syncthreads();
#pragma unroll
    for (int i = 0; i < 4; ++i) {
      const int r = w * 32 + i * 8;
      gl2lds16(A + (size_t)(rowA0 + r + sr) * Kdim + k0 + sc, As + r * 64);
      gl2lds16(B + (size_t)(rowB0 + r + sr) * Kdim + k0 + sc, Bs + r * 64);
    }
    __syncthreads();
#pragma unroll
    for (int kk = 0; kk < 64; kk += 32) {
      bf16x8 af[4], bfr[4];
#pragma unroll
      for (int mi = 0; mi < 4; ++mi)
        af[mi] = *(const bf16x8*)(As + (wrow + mi * 16 + l15) * 64 + kk + quad * 8);
#pragma unroll
      for (int ni = 0; ni < 4; ++ni)
        bfr[ni] = *(const bf16x8*)(Bs + (wcol + ni * 16 + l15) * 64 + kk + quad * 8);
#pragma unroll
      for (int mi = 0; mi < 4; ++mi)
#pragma unroll
        for (int ni = 0; ni < 4; ++ni)
          acc[mi][ni] = __builtin_amdgcn_mfma_f32_16x16x32_bf16(af[mi], bfr[ni], acc[mi][ni], 0, 0, 0);
    }
  }

#pragma unroll
  for (int mi = 0; mi < 4; ++mi)
#pragma unroll
    for (int ni = 0; ni < 4; ++ni)
#pragma unroll
      for (int r = 0; r < 4; ++r) {
        const int row = rowA0 + wrow + mi * 16 + quad * 4 + r;
        const int col = rowB0 + wcol + ni * 16 + l15;
        const float v = acc[mi][ni][r];
        if (MODE == 0) {
          const int sel = col >> 10;
          const size_t idx = (size_t)row * 1024 + (col & 1023);
          if (sel == 0)      ((u16*)Cq)[idx] = f2bf(v * 0.125f);  // Q pre-scaled by 1/sqrt(D)
          else if (sel == 1) Ck[idx] = f2bf(v);
          else               Cv[idx] = f2bf(v);
        } else {
          ((float*)Cq)[(size_t)row * 1024 + col] = v;
        }
      }
}

// ---------------- flash attention (causal, online softmax) ----------------
// grid: x = S/128 q-tiles, y = B*H. block = 256 (4 waves), wave handles 32 q-rows.
__global__ __launch_bounds__(256, 2)
void attn_fwd(const u16* __restrict__ Q, const u16* __restrict__ K,
              const u16* __restrict__ V, u16* __restrict__ Ctx) {
  // Uni: first 8192 elems = K-tile [128][64]; whole 16384 = per-wave P [32][128]
  __shared__ u16 Uni[4 * 32 * 128];
  __shared__ u16 Vt[64 * 128];  // V transposed: Vt[d][t]
  const int tid  = threadIdx.x;
  const int w    = tid >> 6, lane = tid & 63;
  const int quad = lane >> 4, l15 = lane & 15;
  const int sr   = lane >> 3, sc  = (lane & 7) * 8;
  const int qt   = blockIdx.x;
  const int b    = blockIdx.y >> 4, h = blockIdx.y & 15;
  const int q0   = qt * 128;
  const size_t headoff = (size_t)h * 64;

  // preload Q fragments (Q already scaled by 1/sqrt(D))
  bf16x8 a_q[2][2];
#pragma unroll
  for (int mi = 0; mi < 2; ++mi)
#pragma unroll
    for (int ks = 0; ks < 2; ++ks) {
      const int s = q0 + w * 32 + mi * 16 + l15;
      a_q[mi][ks] = *(const bf16x8*)(Q + (size_t)(b * SEQ + s) * EDIM + headoff + ks * 32 + quad * 8);
    }

  const floatx4 vzero = {0.f, 0.f, 0.f, 0.f};
  floatx4 o_acc[2][4];
  float m_run[2][4], l_run[2][4];
#pragma unroll
  for (int mi = 0; mi < 2; ++mi) {
#pragma unroll
    for (int ni = 0; ni < 4; ++ni) o_acc[mi][ni] = vzero;
#pragma unroll
    for (int r = 0; r < 4; ++r) { m_run[mi][r] = -1e30f; l_run[mi][r] = 0.f; }
  }

  for (int kt = 0; kt <= qt; ++kt) {
    const int kbase = b * SEQ + kt * 128;
    __syncthreads();  // prior iter's LDS readers done
    // stage K tile [128][64] via async direct-to-LDS
#pragma unroll
    for (int i = 0; i < 4; ++i) {
      const int r = w * 32 + i * 8;
      gl2lds16(K + (size_t)(kbase + r + sr) * EDIM + headoff + sc, Uni + r * 64);
    }
    // stage V transposed: Vt[d][t]
#pragma unroll
    for (int i = 0; i < 4; ++i) {
      const int cid = i * 256 + tid;       // 0..1023
      const int tl = cid >> 3, c = (cid & 7) * 8;
      union { uint4 v; u16 e[8]; } d;
      d.v = *(const uint4*)(V + (size_t)(kbase + tl) * EDIM + headoff + c);
#pragma unroll
      for (int j = 0; j < 8; ++j) Vt[(c + j) * 128 + tl] = d.e[j];
    }
    __syncthreads();  // drains vmcnt (global_load_lds) + lgkm

    // S = Q * K^T  (32 rows x 128 cols per wave)
    floatx4 s_acc[2][8];
#pragma unroll
    for (int mi = 0; mi < 2; ++mi)
#pragma unroll
      for (int ni = 0; ni < 8; ++ni) s_acc[mi][ni] = vzero;
#pragma unroll
    for (int ks = 0; ks < 2; ++ks) {
      bf16x8 bk[8];
#pragma unroll
      for (int ni = 0; ni < 8; ++ni)
        bk[ni] = *(const bf16x8*)(Uni + (ni * 16 + l15) * 64 + ks * 32 + quad * 8);
#pragma unroll
      for (int mi = 0; mi < 2; ++mi)
#pragma unroll
        for (int ni = 0; ni < 8; ++ni)
          s_acc[mi][ni] = __builtin_amdgcn_mfma_f32_16x16x32_bf16(a_q[mi][ks], bk[ni], s_acc[mi][ni], 0, 0, 0);
    }

    // causal mask (diagonal tile only; local index compare valid since kt==qt)
    if (kt == qt) {
#pragma unroll
      for (int mi = 0; mi < 2; ++mi)
#pragma unroll
        for (int ni = 0; ni < 8; ++ni)
#pragma unroll
          for (int r = 0; r < 4; ++r) {
            const int ql = w * 32 + mi * 16 + quad * 4 + r;
            const int kl = ni * 16 + l15;
            if (kl > ql) s_acc[mi][ni][r] = -1e30f;
          }
    }

    // online softmax: rows live on 16 lanes (same quad), reduce over lane bits 0-3
#pragma unroll
    for (int mi = 0; mi < 2; ++mi)
#pragma unroll
      for (int r = 0; r < 4; ++r) {
        float mx = s_acc[mi][0][r];
#pragma unroll
        for (int ni = 1; ni < 8; ++ni) mx = fmaxf(mx, s_acc[mi][ni][r]);
        mx = fmaxf(mx, __shfl_xor(mx, 1, 64));
        mx = fmaxf(mx, __shfl_xor(mx, 2, 64));
        mx = fmaxf(mx, __shfl_xor(mx, 4, 64));
        mx = fmaxf(mx, __shfl_xor(mx, 8, 64));
        const float mnew  = fmaxf(m_run[mi][r], mx);
        const float alpha = __expf(m_run[mi][r] - mnew);
        m_run[mi][r] = mnew;
        float sum = 0.f;
#pragma unroll
        for (int ni = 0; ni < 8; ++ni) {
          const float p = __expf(s_acc[mi][ni][r] - mnew);
          s_acc[mi][ni][r] = p;
          sum += p;
        }
        sum += __shfl_xor(sum, 1, 64);
        sum += __shfl_xor(sum, 2, 64);
        sum += __shfl_xor(sum, 4, 64);
        sum += __shfl_xor(sum, 8, 64);
        l_run[mi][r] = l_run[mi][r] * alpha + sum;
#pragma unroll
        for (int ni = 0; ni < 4; ++ni) o_acc[mi][ni][r] *= alpha;
      }

    __syncthreads();  // all waves done reading K-tile before P overwrites Uni
    u16* Pw = Uni + w * 4096;
#pragma unroll
    for (int mi = 0; mi < 2; ++mi)
#pragma unroll
      for (int ni = 0; ni < 8; ++ni)
#pragma unroll
        for (int r = 0; r < 4; ++r)
          Pw[(mi * 16 + quad * 4 + r) * 128 + ni * 16 + l15] = f2bf(s_acc[mi][ni][r]);
    __syncthreads();

    // O += P * V
#pragma unroll
    for (int ks = 0; ks < 4; ++ks) {
      bf16x8 pa[2], vb[4];
#pragma unroll
      for (int mi = 0; mi < 2; ++mi)
        pa[mi] = *(const bf16x8*)(Pw + (mi * 16 + l15) * 128 + ks * 32 + quad * 8);
#pragma unroll
      for (int ni = 0; ni < 4; ++ni)
        vb[ni] = *(const bf16x8*)(Vt + (ni * 16 + l15) * 128 + ks * 32 + quad * 8);
#pragma unroll
      for (int mi = 0; mi < 2; ++mi)
#pragma unroll
        for (int ni = 0; ni < 4; ++ni)
          o_acc[mi][ni] = __builtin_amdgcn_mfma_f32_16x16x32_bf16(pa[mi], vb[ni], o_acc[mi][ni], 0, 0, 0);
    }
  }

  // epilogue: O /= l, store ctx bf16 in [B,S,H,D]
#pragma unroll
  for (int mi = 0; mi < 2; ++mi)
#pragma unroll
    for (int r = 0; r < 4; ++r) {
      const float rl = 1.f / l_run[mi][r];
      const int s = q0 + w * 32 + mi * 16 + quad * 4 + r;
      u16* dst = Ctx + (size_t)(b * SEQ + s) * EDIM + headoff;
#pragma unroll
      for (int ni = 0; ni < 4; ++ni)
        dst[ni * 16 + l15] = f2bf(o_acc[mi][ni][r] * rl);
    }
}

// ---------------- launch ----------------
extern "C" void kernel_launch(void* const* d_in, const int* in_sizes, int n_in,
                              void* d_out, int out_size, void* d_ws, size_t ws_size,
                              hipStream_t stream) {
  const float* x  = (const float*)d_in[0];
  const float* Wq = (const float*)d_in[1];
  const float* Wk = (const float*)d_in[2];
  const float* Wv = (const float*)d_in[3];
  const float* Wo = (const float*)d_in[4];
  float* out = (float*)d_out;
  u16* ws = (u16*)d_ws;

  const size_t ME = (size_t)BATCH * SEQ * EDIM;  // 8388608
  u16* Xb   = ws;                                // [8192][1024] bf16
  u16* Wqkv = Xb + ME;                           // [3072][1024]
  u16* Wob  = Wqkv + 3u * 1024 * 1024;           // [1024][1024]
  u16* Qb   = Wob + 1024u * 1024;                // [B,S,H,D] (pre-scaled)
  u16* Kb   = Qb + ME;
  u16* Vb   = Kb + ME;
  u16* Ctx  = Vb + ME;                           // ends at ~88 MB

  cvt_bf16<<<2048, 256, 0, stream>>>(x, Xb, (int)(ME / 4));
  cvt_bf16<<<512, 256, 0, stream>>>(Wq, Wqkv, 262144);
  cvt_bf16<<<512, 256, 0, stream>>>(Wk, Wqkv + 1048576, 262144);
  cvt_bf16<<<512, 256, 0, stream>>>(Wv, Wqkv + 2097152, 262144);
  cvt_bf16<<<512, 256, 0, stream>>>(Wo, Wob, 262144);

  gemm_bt<0><<<dim3(24, 64), 256, 0, stream>>>(Xb, Wqkv, (void*)Qb, Kb, Vb, EDIM);
  attn_fwd<<<dim3(16, 64), 256, 0, stream>>>(Qb, Kb, Vb, Ctx);
  gemm_bt<1><<<dim3(8, 64), 256, 0, stream>>>(Ctx, Wob, (void*)out, nullptr, nullptr, EDIM);
}

// Round 2
// 298.621 us; speedup vs baseline: 1.6555x; 1.6555x over previous
//
#include <hip/hip_runtime.h>
#include <stdint.h>

#define NHEADS 16
#define EDIM   1024
#define SEQ    2048
#define BATCH  4

typedef float  floatx4 __attribute__((ext_vector_type(4)));
typedef __bf16 bf16x8  __attribute__((ext_vector_type(8)));
typedef unsigned short u16;

__device__ __forceinline__ u16 f2bf(float f) {
  union { float f; unsigned int u; } v; v.f = f;
  return (u16)((v.u + 0x7fffu + ((v.u >> 16) & 1u)) >> 16);
}

__device__ __forceinline__ void gl2lds16(const u16* g, u16* l) {
  __builtin_amdgcn_global_load_lds(
      (const __attribute__((address_space(1))) unsigned int*)g,
      (__attribute__((address_space(3))) unsigned int*)l, 16, 0, 0);
}

// ---------------- fp32 -> bf16 conversion (optional scale) ----------------
__global__ void cvt_bf16(const float* __restrict__ src, u16* __restrict__ dst,
                         int n4, float scale) {
  int i = blockIdx.x * blockDim.x + threadIdx.x;
  const int stride = gridDim.x * blockDim.x;
  for (; i < n4; i += stride) {
    float4 f = ((const float4*)src)[i];
    ushort4 o;
    o.x = f2bf(f.x * scale); o.y = f2bf(f.y * scale);
    o.z = f2bf(f.z * scale); o.w = f2bf(f.w * scale);
    ((ushort4*)dst)[i] = o;
  }
}

// ---------------- GEMM: C[M,N] = A[M,K] * B[N,K]^T (bf16 in, fp32 acc) ------
// MODE 0: N=3072 fused QKV -> bf16 stores into Q, K, V buffers (scale folded into Wq)
// MODE 1: fp32 store to Cq
template <int MODE>
__global__ __launch_bounds__(256, 2)
void gemm_bt(const u16* __restrict__ A, const u16* __restrict__ B,
             void* __restrict__ Cq, u16* __restrict__ Ck, u16* __restrict__ Cv,
             int Kdim) {
  __shared__ u16 As[128 * 64];
  __shared__ u16 Bs[128 * 64];
  const int tid  = threadIdx.x;
  const int w    = tid >> 6, lane = tid & 63;
  const int quad = lane >> 4, l15 = lane & 15;
  const int sr   = lane >> 3, sc  = (lane & 7) * 8;
  const int rowA0 = blockIdx.y * 128, rowB0 = blockIdx.x * 128;
  const int wrow  = (w >> 1) * 64,    wcol  = (w & 1) * 64;

  const floatx4 vzero = {0.f, 0.f, 0.f, 0.f};
  floatx4 acc[4][4];
#pragma unroll
  for (int mi = 0; mi < 4; ++mi)
#pragma unroll
    for (int ni = 0; ni < 4; ++ni) acc[mi][ni] = vzero;

  for (int k0 = 0; k0 < Kdim; k0 += 64) {
    __syncthreads();
#pragma unroll
    for (int i = 0; i < 4; ++i) {
      const int r = w * 32 + i * 8;
      gl2lds16(A + (size_t)(rowA0 + r + sr) * Kdim + k0 + sc, As + r * 64);
      gl2lds16(B + (size_t)(rowB0 + r + sr) * Kdim + k0 + sc, Bs + r * 64);
    }
    __syncthreads();
#pragma unroll
    for (int kk = 0; kk < 64; kk += 32) {
      bf16x8 af[4], bfr[4];
#pragma unroll
      for (int mi = 0; mi < 4; ++mi)
        af[mi] = *(const bf16x8*)(As + (wrow + mi * 16 + l15) * 64 + kk + quad * 8);
#pragma unroll
      for (int ni = 0; ni < 4; ++ni)
        bfr[ni] = *(const bf16x8*)(Bs + (wcol + ni * 16 + l15) * 64 + kk + quad * 8);
#pragma unroll
      for (int mi = 0; mi < 4; ++mi)
#pragma unroll
        for (int ni = 0; ni < 4; ++ni)
          acc[mi][ni] = __builtin_amdgcn_mfma_f32_16x16x32_bf16(af[mi], bfr[ni], acc[mi][ni], 0, 0, 0);
    }
  }

#pragma unroll
  for (int mi = 0; mi < 4; ++mi)
#pragma unroll
    for (int ni = 0; ni < 4; ++ni)
#pragma unroll
      for (int r = 0; r < 4; ++r) {
        const int row = rowA0 + wrow + mi * 16 + quad * 4 + r;
        const int col = rowB0 + wcol + ni * 16 + l15;
        const float v = acc[mi][ni][r];
        if (MODE == 0) {
          const int sel = col >> 10;
          u16* dst = sel == 0 ? (u16*)Cq : (sel == 1 ? Ck : Cv);
          dst[(size_t)row * 1024 + (col & 1023)] = f2bf(v);
        } else {
          ((float*)Cq)[(size_t)row * 1024 + col] = v;
        }
      }
}

// ---------------- V transpose: [B,S,H*64+d] -> Vt[(b*16+h)*64+d][S] ----------
__global__ void transpose_v(const u16* __restrict__ Vb, u16* __restrict__ Vt) {
  __shared__ u16 L[64 * 64];
  const int tid = threadIdx.x;
  const int w = tid >> 6, lane = tid & 63;
  const int bh = blockIdx.y, b = bh >> 4, h = bh & 15;
  const int t0 = blockIdx.x * 64;
  // phase 1: coalesced reads, XOR-swizzled vectorized LDS writes
#pragma unroll
  for (int p = 0; p < 2; ++p) {
    const int r = (tid >> 3) + p * 32;  // t-row 0..63
    const int c = tid & 7;              // 16B chunk (8 d-values)
    uint4 v = *(const uint4*)(Vb + (size_t)(b * SEQ + t0 + r) * EDIM + h * 64 + c * 8);
    *(uint4*)(L + r * 64 + ((c ^ (r & 7)) * 8)) = v;
  }
  __syncthreads();
  // phase 2: lane = d, wave covers 16 t's; per-lane contiguous-t uint4 out
  const int d = lane;
#pragma unroll
  for (int jj8 = 0; jj8 < 2; ++jj8) {
    union { uint4 v; u16 e[8]; } tmp;
#pragma unroll
    for (int j = 0; j < 8; ++j) {
      const int t = w * 16 + jj8 * 8 + j;
      tmp.e[j] = L[t * 64 + (((d >> 3) ^ (t & 7)) * 8) + (d & 7)];
    }
    *(uint4*)(Vt + (size_t)(bh * 64 + d) * SEQ + t0 + w * 16 + jj8 * 8) = tmp.v;
  }
}

// ---------------- flash attention (causal, paired q-tiles, flipped MFMA) -----
// grid: x = bh (64), y = pair p (8). Block 256 = 4 waves; wave covers 32 q rows.
// Tile A: qt=p (short), tile B: qt=15-p (long). Every block: 17 compute iters.
__global__ __launch_bounds__(256, 2)
void attn_fwd(const u16* __restrict__ Q, const u16* __restrict__ K,
              const u16* __restrict__ Vt, u16* __restrict__ Ctx) {
  __shared__ u16 Ks[128 * 64];   // K-tile [t][d], 16B-chunk XOR swizzle (row&7)
  __shared__ u16 Vs[64 * 128];   // Vt-tile [d][t], 16B-chunk XOR swizzle (row&15)
  __shared__ u16 Ps[4 * 32 * 128]; // per-wave P [q][t], 8B-subchunk XOR swizzle (q&15)
  const int tid  = threadIdx.x;
  const int w    = tid >> 6, lane = tid & 63;
  const int quad = lane >> 4, l15 = lane & 15;
  const int bh = blockIdx.x, b = bh >> 4, h = bh & 15;
  const int p  = blockIdx.y;
  const int qts[2] = {p, 15 - p};
  u16* Pw = Ps + w * (32 * 128);

  // Q B-fragments for both tiles (Q pre-scaled by 0.125*log2e via Wq cvt)
  bf16x8 bq[2][2][2];
#pragma unroll
  for (int tt = 0; tt < 2; ++tt)
#pragma unroll
    for (int ni = 0; ni < 2; ++ni)
#pragma unroll
      for (int ks = 0; ks < 2; ++ks) {
        const int qs = qts[tt] * 128 + w * 32 + ni * 16 + l15;
        bq[tt][ni][ks] = *(const bf16x8*)(Q + (size_t)(b * SEQ + qs) * EDIM + h * 64 + ks * 32 + quad * 8);
      }

  const floatx4 vzero = {0.f, 0.f, 0.f, 0.f};
  floatx4 o_acc[2][4][2];          // [tile][d-tile][q-tile], O^T C-layout
  float l_run[2][2];
#pragma unroll
  for (int tt = 0; tt < 2; ++tt) {
#pragma unroll
    for (int di = 0; di < 4; ++di)
#pragma unroll
      for (int ni = 0; ni < 2; ++ni) o_acc[tt][di][ni] = vzero;
    l_run[tt][0] = 0.f; l_run[tt][1] = 0.f;
  }

  const int krow = lane >> 3, kch = lane & 7;    // K staging: 8 rows x 8 chunks
  const int vrow = lane >> 4, vch = lane & 15;   // V staging: 4 rows x 16 chunks

  for (int kt = 0; kt <= qts[1]; ++kt) {
    __syncthreads();               // prior iter's K/V readers done
#pragma unroll
    for (int ii = 0; ii < 4; ++ii) {
      const int r0 = w * 32 + ii * 8;
      const int row = r0 + krow;
      gl2lds16(K + (size_t)(b * SEQ + kt * 128 + row) * EDIM + h * 64 + ((kch ^ (row & 7)) * 8),
               Ks + r0 * 64);
      const int d0 = w * 16 + ii * 4;
      const int dd = d0 + vrow;
      gl2lds16(Vt + (size_t)(bh * 64 + dd) * SEQ + kt * 128 + ((vch ^ (dd & 15)) * 8),
               Vs + d0 * 128);
    }
    __syncthreads();               // staging visible to all waves

#pragma unroll
    for (int tt = 1; tt >= 0; --tt) {
      if (tt == 0 && kt > qts[0]) continue;   // uniform branch

      // S^T = K * Q^T : D[t][q], A = K-tile, B = Q
      floatx4 s_acc[8][2];
#pragma unroll
      for (int mi = 0; mi < 8; ++mi)
#pragma unroll
        for (int ni = 0; ni < 2; ++ni) s_acc[mi][ni] = vzero;
#pragma unroll
      for (int ks = 0; ks < 2; ++ks) {
        bf16x8 ak[8];
#pragma unroll
        for (int mi = 0; mi < 8; ++mi)
          ak[mi] = *(const bf16x8*)(Ks + (mi * 16 + l15) * 64 + (((ks * 4 + quad) ^ (l15 & 7)) * 8));
#pragma unroll
        for (int mi = 0; mi < 8; ++mi)
#pragma unroll
          for (int ni = 0; ni < 2; ++ni)
            s_acc[mi][ni] = __builtin_amdgcn_mfma_f32_16x16x32_bf16(ak[mi], bq[tt][ni][ks], s_acc[mi][ni], 0, 0, 0);
      }

      // causal mask on diagonal tile
      if (kt == qts[tt]) {
#pragma unroll
        for (int mi = 0; mi < 8; ++mi)
#pragma unroll
          for (int ni = 0; ni < 2; ++ni)
#pragma unroll
            for (int r = 0; r < 4; ++r) {
              const int t_loc = mi * 16 + quad * 4 + r;
              const int q_loc = w * 32 + ni * 16 + l15;
              if (t_loc > q_loc) s_acc[mi][ni][r] = -1e30f;
            }
      }

      // p = exp2(s'), row-sum via per-lane + cross-quad shuffles; pack P (b64)
#pragma unroll
      for (int ni = 0; ni < 2; ++ni) {
        float ls = 0.f;
#pragma unroll
        for (int mi = 0; mi < 8; ++mi) {
          ushort4 pk;
          float p0 = exp2f(s_acc[mi][ni][0]);
          float p1 = exp2f(s_acc[mi][ni][1]);
          float p2 = exp2f(s_acc[mi][ni][2]);
          float p3 = exp2f(s_acc[mi][ni][3]);
          ls += p0 + p1 + p2 + p3;
          pk.x = f2bf(p0); pk.y = f2bf(p1); pk.z = f2bf(p2); pk.w = f2bf(p3);
          // P[q][t]: q=ni*16+l15, t-subchunk (mi*4+quad) XOR-swizzled by q&15
          *(ushort4*)(Pw + (ni * 16 + l15) * 128 + (((mi * 4 + quad) ^ l15) * 4)) = pk;
        }
        ls += __shfl_xor(ls, 16, 64);
        ls += __shfl_xor(ls, 32, 64);
        l_run[tt][ni] += ls;
      }

      // O^T += Vt * P^T : A = Vs (m=d), B = P (n=q)
#pragma unroll
      for (int ks = 0; ks < 4; ++ks) {
        bf16x8 va[4], pb[2];
#pragma unroll
        for (int di = 0; di < 4; ++di)
          va[di] = *(const bf16x8*)(Vs + (di * 16 + l15) * 128 + (((ks * 4 + quad) ^ l15) * 8));
#pragma unroll
        for (int ni = 0; ni < 2; ++ni) {
          union { uint2 u2[2]; bf16x8 v; } t;
          const u16* base = Pw + (ni * 16 + l15) * 128;
          const int s0 = ks * 8 + quad * 2;
          t.u2[0] = *(const uint2*)(base + ((s0 ^ l15) * 4));
          t.u2[1] = *(const uint2*)(base + (((s0 + 1) ^ l15) * 4));
          pb[ni] = t.v;
        }
#pragma unroll
        for (int di = 0; di < 4; ++di)
#pragma unroll
          for (int ni = 0; ni < 2; ++ni)
            o_acc[tt][di][ni] = __builtin_amdgcn_mfma_f32_16x16x32_bf16(va[di], pb[ni], o_acc[tt][di][ni], 0, 0, 0);
      }
    }
  }

  // epilogue: O = O^T / l, packed b64 stores along d
#pragma unroll
  for (int tt = 0; tt < 2; ++tt)
#pragma unroll
    for (int ni = 0; ni < 2; ++ni) {
      const float rl = 1.f / l_run[tt][ni];
      const int qs = qts[tt] * 128 + w * 32 + ni * 16 + l15;
#pragma unroll
      for (int di = 0; di < 4; ++di) {
        ushort4 ov;
        ov.x = f2bf(o_acc[tt][di][ni][0] * rl);
        ov.y = f2bf(o_acc[tt][di][ni][1] * rl);
        ov.z = f2bf(o_acc[tt][di][ni][2] * rl);
        ov.w = f2bf(o_acc[tt][di][ni][3] * rl);
        *(ushort4*)(Ctx + (size_t)(b * SEQ + qs) * EDIM + h * 64 + di * 16 + quad * 4) = ov;
      }
    }
}

// ---------------- launch ----------------
extern "C" void kernel_launch(void* const* d_in, const int* in_sizes, int n_in,
                              void* d_out, int out_size, void* d_ws, size_t ws_size,
                              hipStream_t stream) {
  const float* x  = (const float*)d_in[0];
  const float* Wq = (const float*)d_in[1];
  const float* Wk = (const float*)d_in[2];
  const float* Wv = (const float*)d_in[3];
  const float* Wo = (const float*)d_in[4];
  float* out = (float*)d_out;
  u16* ws = (u16*)d_ws;

  const size_t ME = (size_t)BATCH * SEQ * EDIM;  // 8388608
  u16* Xb   = ws;                                // [8192][1024] bf16 (reused as Vt)
  u16* Wqkv = Xb + ME;                           // [3072][1024]
  u16* Wob  = Wqkv + 3u * 1024 * 1024;           // [1024][1024]
  u16* Qb   = Wob + 1024u * 1024;                // [B,S,E] (pre-scaled)
  u16* Kb   = Qb + ME;
  u16* Vb   = Kb + ME;
  u16* Ctx  = Vb + ME;
  u16* Vtr  = Xb;                                // Vt aliases Xb (free after QKV GEMM)

  const float qscale = 0.125f * 1.44269504f;     // 1/sqrt(64) * log2(e)

  cvt_bf16<<<2048, 256, 0, stream>>>(x, Xb, (int)(ME / 4), 1.f);
  cvt_bf16<<<512, 256, 0, stream>>>(Wq, Wqkv, 262144, qscale);
  cvt_bf16<<<512, 256, 0, stream>>>(Wk, Wqkv + 1048576, 262144, 1.f);
  cvt_bf16<<<512, 256, 0, stream>>>(Wv, Wqkv + 2097152, 262144, 1.f);
  cvt_bf16<<<512, 256, 0, stream>>>(Wo, Wob, 262144, 1.f);

  gemm_bt<0><<<dim3(24, 64), 256, 0, stream>>>(Xb, Wqkv, (void*)Qb, Kb, Vb, EDIM);
  transpose_v<<<dim3(32, 64), 256, 0, stream>>>(Vb, Vtr);
  attn_fwd<<<dim3(64, 8), 256, 0, stream>>>(Qb, Kb, Vtr, Ctx);
  gemm_bt<1><<<dim3(8, 64), 256, 0, stream>>>(Ctx, Wob, (void*)out, nullptr, nullptr, EDIM);
}

// Round 3
// 237.936 us; speedup vs baseline: 2.0778x; 1.2550x over previous
//
#include <hip/hip_runtime.h>
#include <stdint.h>

#define NHEADS 16
#define EDIM   1024
#define SEQ    2048
#define BATCH  4

typedef float  floatx4 __attribute__((ext_vector_type(4)));
typedef __bf16 bf16x8  __attribute__((ext_vector_type(8)));
typedef unsigned short u16;

__device__ __forceinline__ u16 f2bf(float f) {
  union { float f; unsigned int u; } v; v.f = f;
  return (u16)((v.u + 0x7fffu + ((v.u >> 16) & 1u)) >> 16);
}

// pack two floats -> (bf16(hi)<<16)|bf16(lo), round-half-up, 3 VALU ops
__device__ __forceinline__ unsigned int pkbf(float lo, float hi) {
  union { float f; unsigned int u; } a, c;
  a.f = lo; c.f = hi;
  return __builtin_amdgcn_perm(c.u + 0x8000u, a.u + 0x8000u, 0x07060302u);
}

__device__ __forceinline__ void gl2lds16(const u16* g, u16* l) {
  __builtin_amdgcn_global_load_lds(
      (const __attribute__((address_space(1))) unsigned int*)g,
      (__attribute__((address_space(3))) unsigned int*)l, 16, 0, 0);
}

// ---------------- fused fp32 -> bf16 conversion, 5 regions ----------------
__global__ void cvt_all(const float* __restrict__ x,  const float* __restrict__ wq,
                        const float* __restrict__ wk, const float* __restrict__ wv,
                        const float* __restrict__ wo, u16* __restrict__ xb,
                        u16* __restrict__ wqkv, u16* __restrict__ wob, float qscale) {
  const float* src; u16* dst; int n4; float sc = 1.f;
  switch (blockIdx.y) {
    case 0: src = x;  dst = xb;             n4 = 2097152; break;
    case 1: src = wq; dst = wqkv;           n4 = 262144; sc = qscale; break;
    case 2: src = wk; dst = wqkv + 1048576; n4 = 262144; break;
    case 3: src = wv; dst = wqkv + 2097152; n4 = 262144; break;
    default: src = wo; dst = wob;           n4 = 262144; break;
  }
  const int stride = gridDim.x * blockDim.x;
  for (int i = blockIdx.x * blockDim.x + threadIdx.x; i < n4; i += stride) {
    float4 f = ((const float4*)src)[i];
    uint2 o;
    o.x = pkbf(f.x * sc, f.y * sc);
    o.y = pkbf(f.z * sc, f.w * sc);
    ((uint2*)dst)[i] = o;
  }
}

// ---- GEMM (flipped): D[n][m] = A[n][K] dot B[m][K]; A=weights, B=activations
// C^T register layout: lane col = m(s)-local, rows = n(e)-local -> packed
// stores along output-feature dim.
// MODE 0: A=Wqkv[3072][1024]: e<1024 -> Qb[s][e] (uint2), <2048 -> Kb, else
//         V written TRANSPOSED: Vt[b*1024 + hd][s_loc] (scalar u16).
// MODE 1: A=Wo[1024][1024]: fp32 float4 -> out[s][e].
template <int MODE>
__global__ __launch_bounds__(256, 2)
void gemm_tn(const u16* __restrict__ A, const u16* __restrict__ B,
             void* __restrict__ Cq, u16* __restrict__ Ck, u16* __restrict__ Cv,
             int Kdim) {
  __shared__ u16 As[128 * 64];
  __shared__ u16 Bs[128 * 64];
  const int tid  = threadIdx.x;
  const int w    = tid >> 6, lane = tid & 63;
  const int quad = lane >> 4, l15 = lane & 15;
  const int sr   = lane >> 3, sc8 = lane & 7;
  const int rowA0 = blockIdx.y * 128, rowB0 = blockIdx.x * 128;
  const int wrow  = (w >> 1) * 64,    wcol  = (w & 1) * 64;

  const floatx4 vzero = {0.f, 0.f, 0.f, 0.f};
  floatx4 acc[4][4];
#pragma unroll
  for (int mi = 0; mi < 4; ++mi)
#pragma unroll
    for (int ni = 0; ni < 4; ++ni) acc[mi][ni] = vzero;

  for (int k0 = 0; k0 < Kdim; k0 += 64) {
    __syncthreads();
#pragma unroll
    for (int i = 0; i < 4; ++i) {
      const int r = w * 32 + i * 8;   // 16B-chunk XOR swizzle by row&7 (= sr)
      gl2lds16(A + (size_t)(rowA0 + r + sr) * Kdim + k0 + ((sc8 ^ sr) * 8), As + r * 64);
      gl2lds16(B + (size_t)(rowB0 + r + sr) * Kdim + k0 + ((sc8 ^ sr) * 8), Bs + r * 64);
    }
    __syncthreads();
#pragma unroll
    for (int ks = 0; ks < 2; ++ks) {
      bf16x8 af[4], bfr[4];
#pragma unroll
      for (int mi = 0; mi < 4; ++mi)
        af[mi] = *(const bf16x8*)(As + (wrow + mi * 16 + l15) * 64 + (((ks * 4 + quad) ^ (l15 & 7)) * 8));
#pragma unroll
      for (int ni = 0; ni < 4; ++ni)
        bfr[ni] = *(const bf16x8*)(Bs + (wcol + ni * 16 + l15) * 64 + (((ks * 4 + quad) ^ (l15 & 7)) * 8));
#pragma unroll
      for (int mi = 0; mi < 4; ++mi)
#pragma unroll
        for (int ni = 0; ni < 4; ++ni)
          acc[mi][ni] = __builtin_amdgcn_mfma_f32_16x16x32_bf16(af[mi], bfr[ni], acc[mi][ni], 0, 0, 0);
    }
  }

  const int matid = rowA0 >> 10;  // uniform per block (MODE 0)
#pragma unroll
  for (int mi = 0; mi < 4; ++mi)
#pragma unroll
    for (int ni = 0; ni < 4; ++ni) {
      const int e0 = rowA0 + wrow + mi * 16 + quad * 4;   // 4 consecutive e in r
      const int s  = rowB0 + wcol + ni * 16 + l15;
      if (MODE == 1) {
        *(floatx4*)((float*)Cq + (size_t)s * 1024 + e0) = acc[mi][ni];
      } else {
        const int e_loc = e0 & 1023;
        if (matid < 2) {
          u16* dst = (matid == 0) ? (u16*)Cq : Ck;
          uint2 pk;
          pk.x = pkbf(acc[mi][ni][0], acc[mi][ni][1]);
          pk.y = pkbf(acc[mi][ni][2], acc[mi][ni][3]);
          *(uint2*)(dst + (size_t)s * 1024 + e_loc) = pk;
        } else {
          // V transposed: row = b*1024 + hd, col = s_loc
          const int b = s >> 11, s_loc = s & 2047;
#pragma unroll
          for (int r = 0; r < 4; ++r)
            Cv[(size_t)(b * 1024 + e_loc + r) * SEQ + s_loc] = f2bf(acc[mi][ni][r]);
        }
      }
    }
}

// ---------------- flash attention (causal, paired q-tiles, flipped MFMA) -----
// grid: x = bh (64), y = pair p (8). Block 512 = 8 waves; wave covers 16 q rows.
// Tile 0: qt=p (short), tile 1: qt=15-p (long). Every block: 17 compute iters.
__global__ __launch_bounds__(512, 4)
void attn_fwd(const u16* __restrict__ Q, const u16* __restrict__ K,
              const u16* __restrict__ Vt, u16* __restrict__ Ctx) {
  __shared__ u16 Ks[128 * 64];      // K-tile [t][d], 16B-chunk XOR swizzle (t&7)
  __shared__ u16 Vs[64 * 128];      // Vt-tile [d][t], 16B-chunk XOR swizzle (d&15)
  __shared__ u16 Ps[8 * 16 * 128];  // per-wave P [q][t], 8B-subchunk XOR swizzle (q)
  const int tid  = threadIdx.x;
  const int w    = tid >> 6, lane = tid & 63;
  const int quad = lane >> 4, l15 = lane & 15;
  const int bh = blockIdx.x, b = bh >> 4, h = bh & 15;
  const int p  = blockIdx.y;
  const int qts[2] = {p, 15 - p};
  u16* Pw = Ps + w * (16 * 128);

  // Q B-fragments for both tiles (Q pre-scaled by 0.125*log2e via Wq cvt)
  bf16x8 bq[2][2];
#pragma unroll
  for (int tt = 0; tt < 2; ++tt)
#pragma unroll
    for (int ks = 0; ks < 2; ++ks) {
      const int qs = qts[tt] * 128 + w * 16 + l15;
      bq[tt][ks] = *(const bf16x8*)(Q + (size_t)(b * SEQ + qs) * EDIM + h * 64 + ks * 32 + quad * 8);
    }

  const floatx4 vzero = {0.f, 0.f, 0.f, 0.f};
  floatx4 o_acc[2][4];              // [tile][d-tile], O^T C-layout (col = q)
  float l_run[2] = {0.f, 0.f};
#pragma unroll
  for (int tt = 0; tt < 2; ++tt)
#pragma unroll
    for (int di = 0; di < 4; ++di) o_acc[tt][di] = vzero;

  const int krow = lane >> 3, kch = lane & 7;    // K staging: 8 rows x 8 chunks
  const int vrow = lane >> 4, vch = lane & 15;   // V staging: 4 rows x 16 chunks

  for (int kt = 0; kt <= qts[1]; ++kt) {
    __syncthreads();               // prior iter's K/V readers done
#pragma unroll
    for (int ii = 0; ii < 2; ++ii) {
      const int r0 = w * 16 + ii * 8;
      const int row = r0 + krow;
      gl2lds16(K + (size_t)(b * SEQ + kt * 128 + row) * EDIM + h * 64 + ((kch ^ (row & 7)) * 8),
               Ks + r0 * 64);
      const int d0 = w * 8 + ii * 4;
      const int dd = d0 + vrow;
      gl2lds16(Vt + (size_t)(bh * 64 + dd) * SEQ + kt * 128 + ((vch ^ (dd & 15)) * 8),
               Vs + d0 * 128);
    }
    __syncthreads();               // staging visible to all waves

#pragma unroll
    for (int tt = 1; tt >= 0; --tt) {
      if (tt == 0 && kt > qts[0]) continue;   // uniform branch

      // S^T = K * Q^T : D[t][q], A = K-tile rows(t), B = Q rows(q)
      floatx4 s_acc[8];
#pragma unroll
      for (int mi = 0; mi < 8; ++mi) s_acc[mi] = vzero;
#pragma unroll
      for (int ks = 0; ks < 2; ++ks) {
        bf16x8 ak[8];
#pragma unroll
        for (int mi = 0; mi < 8; ++mi)
          ak[mi] = *(const bf16x8*)(Ks + (mi * 16 + l15) * 64 + (((ks * 4 + quad) ^ (l15 & 7)) * 8));
#pragma unroll
        for (int mi = 0; mi < 8; ++mi)
          s_acc[mi] = __builtin_amdgcn_mfma_f32_16x16x32_bf16(ak[mi], bq[tt][ks], s_acc[mi], 0, 0, 0);
      }

      // causal mask on diagonal tile
      if (kt == qts[tt]) {
        const int q_loc = w * 16 + l15;
#pragma unroll
        for (int mi = 0; mi < 8; ++mi)
#pragma unroll
          for (int r = 0; r < 4; ++r) {
            const int t_loc = mi * 16 + quad * 4 + r;
            if (t_loc > q_loc) s_acc[mi][r] = -1e30f;
          }
      }

      // p = exp2(s'); per-lane sum (col q fixed per lane) + cross-quad shuffles
      float ls = 0.f;
#pragma unroll
      for (int mi = 0; mi < 8; ++mi) {
        float p0 = __builtin_amdgcn_exp2f(s_acc[mi][0]);
        float p1 = __builtin_amdgcn_exp2f(s_acc[mi][1]);
        float p2 = __builtin_amdgcn_exp2f(s_acc[mi][2]);
        float p3 = __builtin_amdgcn_exp2f(s_acc[mi][3]);
        ls += (p0 + p1) + (p2 + p3);
        uint2 pk;
        pk.x = pkbf(p0, p1);
        pk.y = pkbf(p2, p3);
        // P[q=l15][t]: 8B subchunk (mi*4+quad) XOR-swizzled by q
        *(uint2*)(Pw + l15 * 128 + (((mi * 4 + quad) ^ l15) * 4)) = pk;
      }
      ls += __shfl_xor(ls, 16, 64);
      ls += __shfl_xor(ls, 32, 64);
      l_run[tt] += ls;

      // O^T += Vt * P^T : A = Vs rows(d), B = P rows(q)
#pragma unroll
      for (int ks = 0; ks < 4; ++ks) {
        bf16x8 va[4], pb;
#pragma unroll
        for (int di = 0; di < 4; ++di)
          va[di] = *(const bf16x8*)(Vs + (di * 16 + l15) * 128 + (((ks * 4 + quad) ^ l15) * 8));
        {
          union { uint2 u2[2]; bf16x8 v; } t;
          const u16* base = Pw + l15 * 128;
          const int s0 = ks * 8 + quad * 2;
          t.u2[0] = *(const uint2*)(base + ((s0 ^ l15) * 4));
          t.u2[1] = *(const uint2*)(base + (((s0 + 1) ^ l15) * 4));
          pb = t.v;
        }
#pragma unroll
        for (int di = 0; di < 4; ++di)
          o_acc[tt][di] = __builtin_amdgcn_mfma_f32_16x16x32_bf16(va[di], pb, o_acc[tt][di], 0, 0, 0);
      }
    }
  }

  // epilogue: O = O^T / l, packed 8B stores along d
#pragma unroll
  for (int tt = 0; tt < 2; ++tt) {
    const float rl = 1.f / l_run[tt];
    const int qs = qts[tt] * 128 + w * 16 + l15;
#pragma unroll
    for (int di = 0; di < 4; ++di) {
      uint2 ov;
      ov.x = pkbf(o_acc[tt][di][0] * rl, o_acc[tt][di][1] * rl);
      ov.y = pkbf(o_acc[tt][di][2] * rl, o_acc[tt][di][3] * rl);
      *(uint2*)(Ctx + (size_t)(b * SEQ + qs) * EDIM + h * 64 + di * 16 + quad * 4) = ov;
    }
  }
}

// ---------------- launch ----------------
extern "C" void kernel_launch(void* const* d_in, const int* in_sizes, int n_in,
                              void* d_out, int out_size, void* d_ws, size_t ws_size,
                              hipStream_t stream) {
  const float* x  = (const float*)d_in[0];
  const float* Wq = (const float*)d_in[1];
  const float* Wk = (const float*)d_in[2];
  const float* Wv = (const float*)d_in[3];
  const float* Wo = (const float*)d_in[4];
  float* out = (float*)d_out;
  u16* ws = (u16*)d_ws;

  const size_t ME = (size_t)BATCH * SEQ * EDIM;  // 8388608
  u16* Xb   = ws;                                // [8192][1024] bf16
  u16* Wqkv = Xb + ME;                           // [3072][1024]
  u16* Wob  = Wqkv + 3u * 1024 * 1024;           // [1024][1024]
  u16* Qb   = Wob + 1024u * 1024;                // [B,S,E] (pre-scaled)
  u16* Kb   = Qb + ME;
  u16* Vtr  = Kb + ME;                           // V^T: [b*1024 + h*64 + d][2048]
  u16* Ctx  = Vtr + ME;                          // ends at ~88 MB

  const float qscale = 0.125f * 1.44269504f;     // 1/sqrt(64) * log2(e)

  cvt_all<<<dim3(512, 5), 256, 0, stream>>>(x, Wq, Wk, Wv, Wo, Xb, Wqkv, Wob, qscale);
  gemm_tn<0><<<dim3(64, 24), 256, 0, stream>>>(Wqkv, Xb, (void*)Qb, Kb, Vtr, EDIM);
  attn_fwd<<<dim3(64, 8), 512, 0, stream>>>(Qb, Kb, Vtr, Ctx);
  gemm_tn<1><<<dim3(64, 8), 256, 0, stream>>>(Wob, Ctx, (void*)out, nullptr, nullptr, EDIM);
}